// Round 1
// baseline (508.602 us; speedup 1.0000x reference)
//
#include <hip/hip_runtime.h>
#include <math.h>

#define B_GRAPHS 16384
#define N_NODES  524288
#define E_EDGES  1048576
#define D_EMB    128
#define D_STATE  64
#define HID      32
#define CHUNK    32
#define W1PAD    130   // 130 % 32 == 2 -> 2-way LDS bank aliasing (free)

__device__ __forceinline__ int lower_bound_i(const int* __restrict__ a, int n, int v) {
    int lo = 0, hi = n;
    while (lo < hi) {
        int mid = (lo + hi) >> 1;
        if (a[mid] < v) lo = mid + 1; else hi = mid;
    }
    return lo;
}

// ---------------- edge kernel ----------------
// out row e (96 floats = 24 float4): q<8 -> edge_attr[e], q>=8 -> state_emb[state[batch[eidx[e]]]]
// out4[tid] with tid == global float4 index -> perfectly coalesced stores.
__global__ __launch_bounds__(256) void edge_kernel(
    const float4* __restrict__ edge_attr4,   // [E*8]
    const float4* __restrict__ state_emb4,   // [10*16]
    const int*    __restrict__ state,        // [B]
    const int*    __restrict__ eidx,         // [E]
    const int*    __restrict__ batch,        // [N]
    float4*       __restrict__ out4,         // [E*24]
    int total)
{
    int tid = blockIdx.x * 256 + threadIdx.x;
    if (tid >= total) return;
    int e = tid / 24;
    int q = tid - e * 24;
    float4 v;
    if (q < 8) {
        v = edge_attr4[e * 8 + q];
    } else {
        int n = eidx[e];
        int b = batch[n];
        int s = state[b];
        v = state_emb4[s * 16 + (q - 8)];
    }
    out4[tid] = v;
}

// ---------------- graph kernel ----------------
// One block (256 thr) per graph. batch is sorted -> contiguous node range.
// Online softmax over chunks of 32 nodes staged in LDS; z_atom read exactly once.
__global__ __launch_bounds__(256) void graph_kernel(
    const float* __restrict__ z_mol,      // [B,128]
    const float* __restrict__ z_atom,     // [N,128]
    const float* __restrict__ state_emb,  // [10,64]
    const float* __restrict__ W1,         // [192,32]
    const float* __restrict__ b1,         // [32]
    const float* __restrict__ W2,         // [32]
    const float* __restrict__ b2,         // [1]
    const int*   __restrict__ state,      // [B]
    const int*   __restrict__ batch,      // [N] sorted
    float*       __restrict__ out_x)      // [B,256]
{
    __shared__ float s_w1t[HID][W1PAD];      // W1[0:128,:] transposed
    __shared__ float s_hb[HID];              // b1 + zs @ W1[128:192,:]
    __shared__ float s_z[CHUNK][D_EMB];
    __shared__ float s_logit[CHUNK];
    __shared__ float s_p[CHUNK];
    __shared__ float s_accpart[D_EMB];
    __shared__ float s_zs[D_STATE];

    const int g = blockIdx.x;
    const int t = threadIdx.x;

    const int start = lower_bound_i(batch, N_NODES, g);
    const int end   = lower_bound_i(batch, N_NODES, g + 1);

    // stage W1T for k<128 (coalesced global read)
    for (int i = t; i < D_EMB * HID; i += 256) {
        int k = i >> 5, j = i & 31;
        s_w1t[j][k] = W1[i];
    }
    const int st = state[g];
    if (t < D_STATE) s_zs[t] = state_emb[st * D_STATE + t];
    __syncthreads();
    if (t < HID) {
        float hb = b1[t];
        #pragma unroll 8
        for (int k = 0; k < D_STATE; ++k)
            hb += s_zs[k] * W1[(D_EMB + k) * HID + t];
        s_hb[t] = hb;
    }
    __syncthreads();

    const int slot = t >> 5;     // 0..7 node slot
    const int j    = t & 31;     // hidden unit
    const int d    = t & 127;    // emb dim for pooling
    const int half = t >> 7;     // 0/1 node-parity for pooling
    const float w2j = W2[j];
    const float b2v = b2[0];

    float m    = -INFINITY;
    float ssum = 0.f;
    float accd = 0.f;

    for (int c0 = start; c0 < end; c0 += CHUNK) {
        const int cnt = min(CHUNK, end - c0);
        __syncthreads();  // protect s_z / s_p reuse from previous iteration
        {   // stage chunk (contiguous rows, float4 coalesced)
            const float4* za4 = (const float4*)z_atom + (size_t)c0 * (D_EMB / 4);
            float4* sz4 = (float4*)&s_z[0][0];
            for (int i = t; i < cnt * (D_EMB / 4); i += 256)
                sz4[i] = za4[i];
        }
        __syncthreads();

        {   // logits: each slot computes nodes slot, slot+8, slot+16, slot+24
            float h0 = s_hb[j], h1 = h0, h2 = h0, h3 = h0;
            const int n0 = slot, n1 = slot + 8, n2 = slot + 16, n3 = slot + 24;
            const float* wr = &s_w1t[j][0];
            #pragma unroll 8
            for (int k = 0; k < D_EMB; k += 2) {
                float2 w  = *(const float2*)&wr[k];
                float2 z0 = *(const float2*)&s_z[n0][k];
                float2 z1 = *(const float2*)&s_z[n1][k];
                float2 z2 = *(const float2*)&s_z[n2][k];
                float2 z3 = *(const float2*)&s_z[n3][k];
                h0 += z0.x * w.x + z0.y * w.y;
                h1 += z1.x * w.x + z1.y * w.y;
                h2 += z2.x * w.x + z2.y * w.y;
                h3 += z3.x * w.x + z3.y * w.y;
            }
            float c0v = (h0 > 0.f ? h0 : 0.01f * h0) * w2j;
            float c1v = (h1 > 0.f ? h1 : 0.01f * h1) * w2j;
            float c2v = (h2 > 0.f ? h2 : 0.01f * h2) * w2j;
            float c3v = (h3 > 0.f ? h3 : 0.01f * h3) * w2j;
            #pragma unroll
            for (int off = 16; off > 0; off >>= 1) {
                c0v += __shfl_xor(c0v, off);
                c1v += __shfl_xor(c1v, off);
                c2v += __shfl_xor(c2v, off);
                c3v += __shfl_xor(c3v, off);
            }
            if (j == 0) {
                if (n0 < cnt) s_logit[n0] = c0v + b2v;
                if (n1 < cnt) s_logit[n1] = c1v + b2v;
                if (n2 < cnt) s_logit[n2] = c2v + b2v;
                if (n3 < cnt) s_logit[n3] = c3v + b2v;
            }
        }
        __syncthreads();

        float cm = -INFINITY;
        for (int n = 0; n < cnt; ++n) cm = fmaxf(cm, s_logit[n]);
        const float nm    = fmaxf(m, cm);
        const float scale = expf(m - nm);       // m=-inf first iter -> 0
        if (t < cnt) s_p[t] = expf(s_logit[t] - nm);
        __syncthreads();

        float psum = 0.f;
        for (int n = 0; n < cnt; ++n) psum += s_p[n];
        ssum = ssum * scale + psum;
        accd *= scale;
        for (int n = half; n < cnt; n += 2)
            accd += s_p[n] * s_z[n][d];
        m = nm;
    }

    __syncthreads();
    if (half == 1) s_accpart[d] = accd;
    __syncthreads();
    if (t < D_EMB) {
        float v = (accd + s_accpart[t]) / (ssum + 1e-16f);
        out_x[(size_t)g * 256 + D_EMB + t] = v;
    } else {
        out_x[(size_t)g * 256 + (t - 128)] = z_mol[(size_t)g * D_EMB + (t - 128)];
    }
}

extern "C" void kernel_launch(void* const* d_in, const int* in_sizes, int n_in,
                              void* d_out, int out_size, void* d_ws, size_t ws_size,
                              hipStream_t stream)
{
    const float* edge_attr = (const float*)d_in[0];
    const float* z_mol     = (const float*)d_in[1];
    const float* z_atom    = (const float*)d_in[2];
    const float* state_emb = (const float*)d_in[3];
    const float* W1        = (const float*)d_in[4];
    const float* b1        = (const float*)d_in[5];
    const float* W2        = (const float*)d_in[6];
    const float* b2        = (const float*)d_in[7];
    const int*   state     = (const int*)d_in[8];
    const int*   eidx      = (const int*)d_in[9];
    const int*   batch     = (const int*)d_in[10];

    float* out_x = (float*)d_out;
    float* out_e = out_x + (size_t)B_GRAPHS * 256;

    graph_kernel<<<B_GRAPHS, 256, 0, stream>>>(
        z_mol, z_atom, state_emb, W1, b1, W2, b2, state, batch, out_x);

    const int total4 = E_EDGES * 24;  // float4s in edge output
    edge_kernel<<<(total4 + 255) / 256, 256, 0, stream>>>(
        (const float4*)edge_attr, (const float4*)state_emb,
        state, eidx, batch, (float4*)out_e, total4);
}

// Round 2
// 277.935 us; speedup vs baseline: 1.8299x; 1.8299x over previous
//
#include <hip/hip_runtime.h>
#include <math.h>

#define B_GRAPHS 16384
#define N_NODES  524288
#define E_EDGES  1048576
#define D_EMB    128
#define D_STATE  64
#define HID      32
#define CHUNK    32
#define PADK     136      // bf16 elems per LDS row (128 + 8 pad, keeps 16B align: 272 B/row)
#define G_PER    8        // graphs per block

typedef __attribute__((ext_vector_type(8))) short short8;
typedef __attribute__((ext_vector_type(4))) float f32x4;

__device__ __forceinline__ unsigned short f2bf(float f) {
    unsigned int u = __builtin_bit_cast(unsigned int, f);
    u += 0x7fffu + ((u >> 16) & 1u);
    return (unsigned short)(u >> 16);
}
__device__ __forceinline__ float bf2f(unsigned short s) {
    unsigned int u = ((unsigned int)s) << 16;
    return __builtin_bit_cast(float, u);
}

// ---------- K1: segment offsets (batch is sorted) ----------
__global__ __launch_bounds__(256) void offs_kernel(
    const int* __restrict__ batch, int* __restrict__ offs)
{
    int i = blockIdx.x * 256 + threadIdx.x;
    if (i >= N_NODES) return;
    int b = batch[i];
    int prev = (i == 0) ? -1 : batch[i - 1];
    for (int x = prev + 1; x <= b; ++x) offs[x] = i;
    if (i == N_NODES - 1)
        for (int x = b + 1; x <= B_GRAPHS; ++x) offs[x] = N_NODES;
}

// ---------- K2: hb[g][j] = b1[j] + state_emb[state[g]] @ W1[128:192,:] ----------
__global__ __launch_bounds__(256) void hb_kernel(
    const float* __restrict__ state_emb, const float* __restrict__ W1,
    const float* __restrict__ b1, const int* __restrict__ state,
    float* __restrict__ hb)
{
    int t = threadIdx.x;
    int j = t & 31;
    int g = blockIdx.x * 8 + (t >> 5);
    int st = state[g];
    const float* zs = state_emb + st * D_STATE;
    float acc = b1[j];
    #pragma unroll 8
    for (int k = 0; k < D_STATE; ++k)
        acc += zs[k] * W1[(D_EMB + k) * HID + j];
    hb[g * HID + j] = acc;
}

// ---------- K3: fused logits(MFMA bf16) + segment softmax + weighted pooling ----------
__global__ __launch_bounds__(256) void graph_kernel(
    const float* __restrict__ z_mol,
    const float* __restrict__ z_atom,
    const float* __restrict__ W1,
    const float* __restrict__ W2,
    const float* __restrict__ b2,
    const int*   __restrict__ offs,
    const float* __restrict__ hb,
    float*       __restrict__ out_x)
{
    __shared__ unsigned short s_w1t[HID][PADK];   // W1[0:128,:]^T bf16: [j][k]
    __shared__ unsigned short s_zb[CHUNK][PADK];  // z chunk bf16: [n][k]
    __shared__ float s_lp[4][16];                 // per-wave logit partials
    __shared__ float s_p[CHUNK];
    __shared__ float s_hb[HID];
    __shared__ float s_w2[HID];
    __shared__ float s_accp[8][D_EMB];
    __shared__ float s_scale;
    __shared__ float s_ssum;

    const int t    = threadIdx.x;
    const int lane = t & 63;
    const int w    = t >> 6;          // wave 0..3
    const int jh   = w & 1;           // j-half of output tile
    const int nh   = w >> 1;          // node-half
    const int l15  = lane & 15;
    const int kc   = lane >> 4;       // 0..3

    // pooling mapping: 4 consecutive emb dims per thread
    const int dg = t & 31;            // d = dg*4 .. dg*4+3
    const int np = t >> 5;            // node stripe 0..7

    // stage W1T (k<128) as bf16 once per block
    for (int i = t; i < D_EMB * HID; i += 256) {
        int k = i >> 5, j = i & 31;
        s_w1t[j][k] = f2bf(W1[i]);    // W1 row-major [k][j]
    }
    if (t < HID) s_w2[t] = W2[t];
    const float b2v = b2[0];

    for (int gi = 0; gi < G_PER; ++gi) {
        const int g = blockIdx.x * G_PER + gi;
        const int start = offs[g], end = offs[g + 1];
        if (t < HID) s_hb[t] = hb[g * HID + t];

        float a0 = 0.f, a1 = 0.f, a2 = 0.f, a3 = 0.f;   // pooling acc (4 dims)
        float m = -INFINITY, ssum = 0.f;                 // live in wave 0

        for (int c0 = start; c0 < end; c0 += CHUNK) {
            const int cnt = min(CHUNK, end - c0);
            __syncthreads();   // S1: s_zb free, s_hb visible

            // stage chunk: f32 global (coalesced float4) -> bf16 LDS; zero-fill tail
            const float4* za4 = (const float4*)z_atom + (size_t)c0 * (D_EMB / 4);
            #pragma unroll
            for (int rep = 0; rep < 4; ++rep) {
                int i = t + rep * 256;          // 0..1023
                int n = i >> 5, c = i & 31;
                float4 v = make_float4(0.f, 0.f, 0.f, 0.f);
                if (n < cnt) v = za4[n * (D_EMB / 4) + c];
                unsigned int lo = (unsigned)f2bf(v.x) | ((unsigned)f2bf(v.y) << 16);
                unsigned int hi = (unsigned)f2bf(v.z) | ((unsigned)f2bf(v.w) << 16);
                *(uint2*)&s_zb[n][c * 4] = make_uint2(lo, hi);
            }
            __syncthreads();   // S2

            // D = W1T_tile(16j x 32k) * ZT_tile(32k x 16n); wave w owns (jh,nh) tile
            f32x4 acc = {0.f, 0.f, 0.f, 0.f};
            #pragma unroll
            for (int ks = 0; ks < 4; ++ks) {
                short8 af = *(const short8*)&s_w1t[l15 + 16 * jh][ks * 32 + kc * 8];
                short8 bfr = *(const short8*)&s_zb[l15 + 16 * nh][ks * 32 + kc * 8];
                acc = __builtin_amdgcn_mfma_f32_16x16x32_bf16(af, bfr, acc, 0, 0, 0);
            }
            // lane holds h[j = 16*jh + kc*4 + r][n = l15 + 16*nh]
            float p = 0.f;
            #pragma unroll
            for (int r = 0; r < 4; ++r) {
                int j = 16 * jh + kc * 4 + r;
                float h = acc[r] + s_hb[j];
                h = h > 0.f ? h : 0.01f * h;
                p += h * s_w2[j];
            }
            p += __shfl_xor(p, 16);   // sum over kc (j quartets)
            p += __shfl_xor(p, 32);
            if (kc == 0 && lane < 16) s_lp[w][l15] = p;   // per (jh,nh) partial
            __syncthreads();   // S3

            if (w == 0) {   // online softmax on wave 0 (lane = node for lane<32)
                float v;
                if (lane < 32 && lane < cnt) {
                    int nloc = lane & 15, nhh = lane >> 4;
                    v = s_lp[2 * nhh][nloc] + s_lp[2 * nhh + 1][nloc] + b2v;
                } else v = -INFINITY;
                float cm = v;
                #pragma unroll
                for (int off = 32; off > 0; off >>= 1)
                    cm = fmaxf(cm, __shfl_xor(cm, off));
                float nm = fmaxf(m, cm);
                float sc = expf(m - nm);        // first chunk: exp(-inf)=0
                float pp = expf(v - nm);        // masked lanes -> 0
                float ps = pp;
                #pragma unroll
                for (int off = 32; off > 0; off >>= 1)
                    ps += __shfl_xor(ps, off);
                ssum = ssum * sc + ps;
                m = nm;
                if (lane < 32) s_p[lane] = pp;
                if (lane == 0) s_scale = sc;
            }
            __syncthreads();   // S4

            // pooling: acc = acc*scale + sum_n p[n] * z[n][d]
            const float sc = s_scale;
            a0 *= sc; a1 *= sc; a2 *= sc; a3 *= sc;
            #pragma unroll
            for (int it = 0; it < 4; ++it) {
                int n = np + it * 8;
                float pn = s_p[n];               // 0 for n >= cnt
                uint2 zz = *(const uint2*)&s_zb[n][dg * 4];
                a0 += pn * bf2f((unsigned short)(zz.x & 0xffffu));
                a1 += pn * bf2f((unsigned short)(zz.x >> 16));
                a2 += pn * bf2f((unsigned short)(zz.y & 0xffffu));
                a3 += pn * bf2f((unsigned short)(zz.y >> 16));
            }
        }

        __syncthreads();   // E1: pooling (and prev epilogue reads) done
        s_accp[np][dg * 4 + 0] = a0;
        s_accp[np][dg * 4 + 1] = a1;
        s_accp[np][dg * 4 + 2] = a2;
        s_accp[np][dg * 4 + 3] = a3;
        if (t == 0) s_ssum = ssum;
        __syncthreads();   // E2

        if (t < D_EMB) {
            float tot = 0.f;
            #pragma unroll
            for (int q = 0; q < 8; ++q) tot += s_accp[q][t];
            out_x[(size_t)g * 256 + D_EMB + t] = tot / (s_ssum + 1e-16f);
        } else {
            int d = t - 128;
            out_x[(size_t)g * 256 + d] = z_mol[(size_t)g * D_EMB + d];
        }
    }
}

// ---------- K4: edge concat ----------
__global__ __launch_bounds__(256) void edge_kernel(
    const float4* __restrict__ edge_attr4,
    const float4* __restrict__ state_emb4,
    const int*    __restrict__ state,
    const int*    __restrict__ eidx,
    const int*    __restrict__ batch,
    float4*       __restrict__ out4,
    int total)
{
    int tid = blockIdx.x * 256 + threadIdx.x;
    if (tid >= total) return;
    int e = tid / 24;
    int q = tid - e * 24;
    float4 v;
    if (q < 8) {
        v = edge_attr4[e * 8 + q];
    } else {
        int n = eidx[e];
        int b = batch[n];
        int s = state[b];
        v = state_emb4[s * 16 + (q - 8)];
    }
    out4[tid] = v;
}

extern "C" void kernel_launch(void* const* d_in, const int* in_sizes, int n_in,
                              void* d_out, int out_size, void* d_ws, size_t ws_size,
                              hipStream_t stream)
{
    const float* edge_attr = (const float*)d_in[0];
    const float* z_mol     = (const float*)d_in[1];
    const float* z_atom    = (const float*)d_in[2];
    const float* state_emb = (const float*)d_in[3];
    const float* W1        = (const float*)d_in[4];
    const float* b1        = (const float*)d_in[5];
    const float* W2        = (const float*)d_in[6];
    const float* b2        = (const float*)d_in[7];
    const int*   state     = (const int*)d_in[8];
    const int*   eidx      = (const int*)d_in[9];
    const int*   batch     = (const int*)d_in[10];

    float* out_x = (float*)d_out;
    float* out_e = out_x + (size_t)B_GRAPHS * 256;

    int*   offs = (int*)d_ws;                               // (B+1) ints = 65540 B
    float* hbuf = (float*)((char*)d_ws + 65552);            // B*32 floats = 2 MB

    offs_kernel<<<N_NODES / 256, 256, 0, stream>>>(batch, offs);
    hb_kernel<<<B_GRAPHS / 8, 256, 0, stream>>>(state_emb, W1, b1, state, hbuf);
    graph_kernel<<<B_GRAPHS / G_PER, 256, 0, stream>>>(
        z_mol, z_atom, W1, W2, b2, offs, hbuf, out_x);

    const int total4 = E_EDGES * 24;
    edge_kernel<<<(total4 + 255) / 256, 256, 0, stream>>>(
        (const float4*)edge_attr, (const float4*)state_emb,
        state, eidx, batch, (float4*)out_e, total4);
}